// Round 13
// baseline (521.134 us; speedup 1.0000x reference)
//
#include <hip/hip_runtime.h>

// LSTM: B=2048, T=512, I=1, H=64, L=2, O=1. fp32 in/out.
// Round 13: r12 + padding-lane broadcast + bias-in-accumulator.
//   r12 analysis: step = 2367 cyc, LDS pipe ~1450 (96 ds_read_b128, BW-
//   limited at ~85 B/cyc) co-limits with VALU ~1400. But HALF the B-frag
//   read bytes are the zero padding columns (batches 8..15 of the N=16
//   tile). Those D columns are discarded, so their B values are
//   irrelevant: lanes with n>=8 now read the SAME addresses as their
//   n-8 partners (rla = lane & ~8). Same-address LDS reads broadcast
//   (served once) -> read bytes halve. D cols 8-15 become duplicates of
//   0-7; the DPP pack discards them exactly as before.
//   Also: accumulators init with bias in D-layout (biasD[r] =
//   bias[r*64+4*mtg+q], which rides the ror8 pack to the right (j,gate))
//   -> post-pack bias adds deleted.
// Design otherwise unchanged from r12 (PASS, 490 us):
//   16 waves (4/SIMD), 2 M-tiles/wave, ONE barrier/step, L2 skewed:
//   waves 0-7 : G1 = Whh0*h1(k-1) (+x) -> h1(k)   -> aH1[pn]
//   waves 8-15: G2 = Wih1*h1(k-1)+Whh1*h2(k-2) -> h2(k-1) -> aH2[pn]
// fp32 accuracy via bf16 hi+lo 3-product split. DPP must run with all
// 64 lanes active (convergent; inactive source lanes read 0).

#define TT 512
#define HH 64
#define BT 8

typedef __attribute__((ext_vector_type(8))) short short8;
typedef __attribute__((ext_vector_type(4))) float f32x4;

#define MFMA16 __builtin_amdgcn_mfma_f32_16x16x32_bf16

__device__ __forceinline__ float sigm(float x) {
    return __builtin_amdgcn_rcpf(1.f + __expf(-x));
}
// NaN-safe tanh: 1 - 2/(1+e^{2x})
__device__ __forceinline__ float tanh_f(float x) {
    return 1.f - 2.f * __builtin_amdgcn_rcpf(1.f + __expf(2.f * x));
}
__device__ __forceinline__ void cvt8(const float* p, short8& hi, short8& lo) {
    #pragma unroll
    for (int i = 0; i < 8; ++i) {
        float v = p[i];
        unsigned short h = (unsigned short)(__float_as_uint(v) >> 16);
        float r = v - __uint_as_float(((unsigned)h) << 16);
        unsigned short l = (unsigned short)(__float_as_uint(r) >> 16);
        hi[i] = (short)h;
        lo[i] = (short)l;
    }
}
__device__ __forceinline__ void split1(float v, unsigned short& h, unsigned short& l) {
    h = (unsigned short)(__float_as_uint(v) >> 16);
    float r = v - __uint_as_float(((unsigned)h) << 16);
    l = (unsigned short)(__float_as_uint(r) >> 16);
}
__device__ __forceinline__ float gate4(float pi, float pf, float pg, float po, float& c) {
    float gi = sigm(pi), gf = sigm(pf), gg = tanh_f(pg), go = sigm(po);
    c = fmaf(gf, c, gi * gg);
    return go * tanh_f(c);
}
// lane i <- lane (i^8) within each row of 16 (row_ror:8). All lanes must
// be active at the call site.
__device__ __forceinline__ float dpp_ror8(float v) {
    return __int_as_float(__builtin_amdgcn_update_dpp(
        0, __float_as_int(v), 0x128, 0xF, 0xF, true));
}

__global__ __launch_bounds__(1024) void lstm_mfma(
    const float* __restrict__ x,
    const float* __restrict__ Wih0, const float* __restrict__ Whh0,
    const float* __restrict__ bih0, const float* __restrict__ bhh0,
    const float* __restrict__ Wih1, const float* __restrict__ Whh1,
    const float* __restrict__ bih1, const float* __restrict__ bhh1,
    const float* __restrict__ fcW, const float* __restrict__ fcb,
    float* __restrict__ out)
{
    __shared__ float xs[BT][TT + 1];                     // 16.4 KB
    // h in MFMA B-layout: [buf][kt][hi/lo][lane][elem]; B[k][n]: n=lane&15,
    // k = kt*32 + (lane>>4)*8 + elem. Rows for n>=8 never written/read.
    __shared__ __align__(16) short aH1[2][2][2][64][8];  // 8 KB
    __shared__ __align__(16) short aH2[2][2][2][64][8];  // 8 KB
    __shared__ float hF[BT][HH + 1];
    __shared__ float fcw_s[HH];

    const int t    = threadIdx.x;
    const int lane = t & 63;
    const int w    = t >> 6;          // wave 0..15
    const bool isL1 = (w < 8);
    const int wv   = w & 7;           // group-local wave: owns M-tiles 2wv, 2wv+1
    const int b0   = blockIdx.x * BT;
    const int m    = lane & 15;       // A-row-within-tile AND D-col (=batch)
    const int q    = lane >> 4;       // quad
    // broadcast read lane: padding columns (bit3 of n set) read partner's
    // address -> same-address broadcast, half the LDS read bytes.
    const int rla  = lane & ~8;

    // ---- stage x; zero both h buffers ----
    for (int i = t; i < BT * TT; i += 1024)
        xs[i >> 9][i & (TT - 1)] = x[(size_t)(b0 + (i >> 9)) * TT + (i & (TT - 1))];
    {
        int* z1 = (int*)aH1;
        for (int i = t; i < 2048; i += 1024) z1[i] = 0;
        int* z2 = (int*)aH2;
        for (int i = t; i < 2048; i += 1024) z2[i] = 0;
    }
    if (t < HH) fcw_s[t] = fcW[t];

    // ---- persistent A-frag weights (hi/lo): 2 tiles per wave ----
    // A-row m in tile mtg -> gate-row rho = (m&3)*64 + 4*mtg + (m>>2)
    // G1 (isL1): kt 0,1 from Whh0.  G2: kt 0,1 Wih1; kt 2,3 Whh1.
    short8 aWh[2][4], aWl[2][4];      // [i][kt]
    {
        const float* Ws01 = isL1 ? Whh0 : Wih1;
        #pragma unroll
        for (int i = 0; i < 2; ++i) {
            const int mtg = 2 * wv + i;
            const int rho = (m & 3) * 64 + 4 * mtg + (m >> 2);
            cvt8(Ws01 + rho * HH +      q * 8, aWh[i][0], aWl[i][0]);
            cvt8(Ws01 + rho * HH + 32 + q * 8, aWh[i][1], aWl[i][1]);
            if (!isL1) {
                cvt8(Whh1 + rho * HH +      q * 8, aWh[i][2], aWl[i][2]);
                cvt8(Whh1 + rho * HH + 32 + q * 8, aWh[i][3], aWl[i][3]);
            }
        }
    }

    // ---- bias in D-layout (rides the pack): biasD[i][r] for tile i,
    // D-row 4q+r -> gate-row rho = r*64 + 4*(2wv+i) + q ----
    f32x4 biasD[2];
    #pragma unroll
    for (int i = 0; i < 2; ++i)
        #pragma unroll
        for (int r = 0; r < 4; ++r) {
            const int rho = r * 64 + 4 * (2 * wv + i) + q;
            biasD[i][r] = isL1 ? (bih0[rho] + bhh0[rho])
                               : (bih1[rho] + bhh1[rho]);
        }

    // ---- packed combine constants: lane handles (jpk, bpk) ----
    const int ts  = (m >> 3) & 1;
    const int jpk = 8 * wv + 4 * ts + q;   // this lane's hidden unit
    const int bpk = m & 7;                 // this lane's batch
    float wxb[4];
    #pragma unroll
    for (int v = 0; v < 4; ++v)
        wxb[v] = isL1 ? Wih0[v * 64 + jpk] : 0.f;
    // scatter indices for (jpk, bpk) into B-layout
    const int skt = jpk >> 5;
    const int ssl = bpk + 16 * ((jpk >> 3) & 3);
    const int sse = jpk & 7;
    float c = 0.f;

    __syncthreads();

    #pragma unroll 2
    for (int k = 0; k < TT; ++k) {
        const int p = k & 1, pn = p ^ 1;

        if (isL1) {
            // ---- G1: h1(k) from h1(k-1) ----
            short8 bh0 = *(const short8*)&aH1[p][0][0][rla][0];
            short8 bl0 = *(const short8*)&aH1[p][0][1][rla][0];
            short8 bh1 = *(const short8*)&aH1[p][1][0][rla][0];
            short8 bl1 = *(const short8*)&aH1[p][1][1][rla][0];
            f32x4 acc0 = biasD[0], acc1 = biasD[1];
            acc0 = MFMA16(aWh[0][0], bh0, acc0, 0, 0, 0);
            acc0 = MFMA16(aWl[0][0], bh0, acc0, 0, 0, 0);
            acc0 = MFMA16(aWh[0][0], bl0, acc0, 0, 0, 0);
            acc0 = MFMA16(aWh[0][1], bh1, acc0, 0, 0, 0);
            acc0 = MFMA16(aWl[0][1], bh1, acc0, 0, 0, 0);
            acc0 = MFMA16(aWh[0][1], bl1, acc0, 0, 0, 0);
            acc1 = MFMA16(aWh[1][0], bh0, acc1, 0, 0, 0);
            acc1 = MFMA16(aWl[1][0], bh0, acc1, 0, 0, 0);
            acc1 = MFMA16(aWh[1][0], bl0, acc1, 0, 0, 0);
            acc1 = MFMA16(aWh[1][1], bh1, acc1, 0, 0, 0);
            acc1 = MFMA16(aWl[1][1], bh1, acc1, 0, 0, 0);
            acc1 = MFMA16(aWh[1][1], bl1, acc1, 0, 0, 0);
            // DPP unconditionally (all lanes active), THEN select.
            f32x4 mv, pk;
            #pragma unroll
            for (int r = 0; r < 4; ++r) mv[r] = dpp_ror8(acc1[r]);
            #pragma unroll
            for (int r = 0; r < 4; ++r) pk[r] = (m < 8) ? acc0[r] : mv[r];
            float xb = xs[bpk][k];
            float h1 = gate4(fmaf(wxb[0], xb, pk[0]),
                             fmaf(wxb[1], xb, pk[1]),
                             fmaf(wxb[2], xb, pk[2]),
                             fmaf(wxb[3], xb, pk[3]), c);
            unsigned short hh, hl;
            split1(h1, hh, hl);
            aH1[pn][skt][0][ssl][sse] = (short)hh;
            aH1[pn][skt][1][ssl][sse] = (short)hl;
        } else if (k > 0) {
            // ---- G2: h2(k-1) from h1(k-1), h2(k-2) ----
            short8 b1h0 = *(const short8*)&aH1[p][0][0][rla][0];
            short8 b1l0 = *(const short8*)&aH1[p][0][1][rla][0];
            short8 b1h1 = *(const short8*)&aH1[p][1][0][rla][0];
            short8 b1l1 = *(const short8*)&aH1[p][1][1][rla][0];
            short8 b2h0 = *(const short8*)&aH2[p][0][0][rla][0];
            short8 b2l0 = *(const short8*)&aH2[p][0][1][rla][0];
            short8 b2h1 = *(const short8*)&aH2[p][1][0][rla][0];
            short8 b2l1 = *(const short8*)&aH2[p][1][1][rla][0];
            f32x4 acc0 = biasD[0], acc1 = biasD[1];
            acc0 = MFMA16(aWh[0][0], b1h0, acc0, 0, 0, 0);
            acc0 = MFMA16(aWl[0][0], b1h0, acc0, 0, 0, 0);
            acc0 = MFMA16(aWh[0][0], b1l0, acc0, 0, 0, 0);
            acc0 = MFMA16(aWh[0][1], b1h1, acc0, 0, 0, 0);
            acc0 = MFMA16(aWl[0][1], b1h1, acc0, 0, 0, 0);
            acc0 = MFMA16(aWh[0][1], b1l1, acc0, 0, 0, 0);
            acc0 = MFMA16(aWh[0][2], b2h0, acc0, 0, 0, 0);
            acc0 = MFMA16(aWl[0][2], b2h0, acc0, 0, 0, 0);
            acc0 = MFMA16(aWh[0][2], b2l0, acc0, 0, 0, 0);
            acc0 = MFMA16(aWh[0][3], b2h1, acc0, 0, 0, 0);
            acc0 = MFMA16(aWl[0][3], b2h1, acc0, 0, 0, 0);
            acc0 = MFMA16(aWh[0][3], b2l1, acc0, 0, 0, 0);
            acc1 = MFMA16(aWh[1][0], b1h0, acc1, 0, 0, 0);
            acc1 = MFMA16(aWl[1][0], b1h0, acc1, 0, 0, 0);
            acc1 = MFMA16(aWh[1][0], b1l0, acc1, 0, 0, 0);
            acc1 = MFMA16(aWh[1][1], b1h1, acc1, 0, 0, 0);
            acc1 = MFMA16(aWl[1][1], b1h1, acc1, 0, 0, 0);
            acc1 = MFMA16(aWh[1][1], b1l1, acc1, 0, 0, 0);
            acc1 = MFMA16(aWh[1][2], b2h0, acc1, 0, 0, 0);
            acc1 = MFMA16(aWl[1][2], b2h0, acc1, 0, 0, 0);
            acc1 = MFMA16(aWh[1][2], b2l0, acc1, 0, 0, 0);
            acc1 = MFMA16(aWh[1][3], b2h1, acc1, 0, 0, 0);
            acc1 = MFMA16(aWl[1][3], b2h1, acc1, 0, 0, 0);
            acc1 = MFMA16(aWh[1][3], b2l1, acc1, 0, 0, 0);
            f32x4 mv, pk;
            #pragma unroll
            for (int r = 0; r < 4; ++r) mv[r] = dpp_ror8(acc1[r]);
            #pragma unroll
            for (int r = 0; r < 4; ++r) pk[r] = (m < 8) ? acc0[r] : mv[r];
            float h2 = gate4(pk[0], pk[1], pk[2], pk[3], c);
            unsigned short hh, hl;
            split1(h2, hh, hl);
            aH2[pn][skt][0][ssl][sse] = (short)hh;
            aH2[pn][skt][1][ssl][sse] = (short)hl;
        }
        __syncthreads();
    }

    // ---- epilogue: h2(TT-1) from h1(TT-1) (aH1[0]) and h2(TT-2) (aH2[0]) ----
    if (!isL1) {
        short8 b1h0 = *(const short8*)&aH1[0][0][0][rla][0];
        short8 b1l0 = *(const short8*)&aH1[0][0][1][rla][0];
        short8 b1h1 = *(const short8*)&aH1[0][1][0][rla][0];
        short8 b1l1 = *(const short8*)&aH1[0][1][1][rla][0];
        short8 b2h0 = *(const short8*)&aH2[0][0][0][rla][0];
        short8 b2l0 = *(const short8*)&aH2[0][0][1][rla][0];
        short8 b2h1 = *(const short8*)&aH2[0][1][0][rla][0];
        short8 b2l1 = *(const short8*)&aH2[0][1][1][rla][0];
        f32x4 acc0 = biasD[0], acc1 = biasD[1];
        acc0 = MFMA16(aWh[0][0], b1h0, acc0, 0, 0, 0);
        acc0 = MFMA16(aWl[0][0], b1h0, acc0, 0, 0, 0);
        acc0 = MFMA16(aWh[0][0], b1l0, acc0, 0, 0, 0);
        acc0 = MFMA16(aWh[0][1], b1h1, acc0, 0, 0, 0);
        acc0 = MFMA16(aWl[0][1], b1h1, acc0, 0, 0, 0);
        acc0 = MFMA16(aWh[0][1], b1l1, acc0, 0, 0, 0);
        acc0 = MFMA16(aWh[0][2], b2h0, acc0, 0, 0, 0);
        acc0 = MFMA16(aWl[0][2], b2h0, acc0, 0, 0, 0);
        acc0 = MFMA16(aWh[0][2], b2l0, acc0, 0, 0, 0);
        acc0 = MFMA16(aWh[0][3], b2h1, acc0, 0, 0, 0);
        acc0 = MFMA16(aWl[0][3], b2h1, acc0, 0, 0, 0);
        acc0 = MFMA16(aWh[0][3], b2l1, acc0, 0, 0, 0);
        acc1 = MFMA16(aWh[1][0], b1h0, acc1, 0, 0, 0);
        acc1 = MFMA16(aWl[1][0], b1h0, acc1, 0, 0, 0);
        acc1 = MFMA16(aWh[1][0], b1l0, acc1, 0, 0, 0);
        acc1 = MFMA16(aWh[1][1], b1h1, acc1, 0, 0, 0);
        acc1 = MFMA16(aWl[1][1], b1h1, acc1, 0, 0, 0);
        acc1 = MFMA16(aWh[1][1], b1l1, acc1, 0, 0, 0);
        acc1 = MFMA16(aWh[1][2], b2h0, acc1, 0, 0, 0);
        acc1 = MFMA16(aWl[1][2], b2h0, acc1, 0, 0, 0);
        acc1 = MFMA16(aWh[1][2], b2l0, acc1, 0, 0, 0);
        acc1 = MFMA16(aWh[1][3], b2h1, acc1, 0, 0, 0);
        acc1 = MFMA16(aWl[1][3], b2h1, acc1, 0, 0, 0);
        acc1 = MFMA16(aWh[1][3], b2l1, acc1, 0, 0, 0);
        f32x4 mv, pk;
        #pragma unroll
        for (int r = 0; r < 4; ++r) mv[r] = dpp_ror8(acc1[r]);
        #pragma unroll
        for (int r = 0; r < 4; ++r) pk[r] = (m < 8) ? acc0[r] : mv[r];
        float h2 = gate4(pk[0], pk[1], pk[2], pk[3], c);
        hF[bpk][jpk] = h2;
    }
    __syncthreads();

    // ---- final FC: out[b] = fcW . h2(TT-1)[b] + fcb ----
    if (t < BT) {
        float s = fcb[0];
        #pragma unroll 8
        for (int j = 0; j < HH; ++j)
            s = fmaf(hF[t][j], fcw_s[j], s);
        out[b0 + t] = s;
    }
}

extern "C" void kernel_launch(void* const* d_in, const int* in_sizes, int n_in,
                              void* d_out, int out_size, void* d_ws, size_t ws_size,
                              hipStream_t stream) {
    const float* x    = (const float*)d_in[0];
    const float* Wih0 = (const float*)d_in[1];
    const float* Whh0 = (const float*)d_in[2];
    const float* bih0 = (const float*)d_in[3];
    const float* bhh0 = (const float*)d_in[4];
    const float* Wih1 = (const float*)d_in[5];
    const float* Whh1 = (const float*)d_in[6];
    const float* bih1 = (const float*)d_in[7];
    const float* bhh1 = (const float*)d_in[8];
    const float* fcW  = (const float*)d_in[9];
    const float* fcb  = (const float*)d_in[10];
    float* out = (float*)d_out;

    lstm_mfma<<<dim3(2048 / BT), dim3(1024), 0, stream>>>(
        x, Wih0, Whh0, bih0, bhh0, Wih1, Whh1, bih1, bhh1, fcW, fcb, out);
}

// Round 14
// 505.486 us; speedup vs baseline: 1.0310x; 1.0310x over previous
//
#include <hip/hip_runtime.h>

// LSTM: B=2048, T=512, I=1, H=64, L=2, O=1. fp32 in/out.
// Round 14: revert r13's broadcast-read (ds_read_b128 same-address reads
// do NOT merge: 32 distinct addrs x 4-bank span doubled per-bank pressure,
// SQ_LDS_BANK_CONFLICT 12K -> 5e7, +46us). Keep r13's bias-in-accumulator
// (register-neutral, -8 VALU/wave/step).
// Register budget lesson (r12): VGPR 64 + AGPR 64 weights = 128/wave =
// exactly 4 waves/SIMD. Any extra VGPR drops occupancy -> all changes
// must be register-neutral.
// Design (r12, PASS 490us):
//   16 waves (4/SIMD), 2 M-tiles/wave, ONE barrier/step, L2 skewed:
//   waves 0-7 : G1 = Whh0*h1(k-1) (+x) -> h1(k)   -> aH1[pn]
//   waves 8-15: G2 = Wih1*h1(k-1)+Whh1*h2(k-2) -> h2(k-1) -> aH2[pn]
//   transposed MFMA (D = W*h): gates land in-lane (f32x4 = i,f,g,o),
//   junk D-cols 8..15 folded via ror:8 DPP (run with ALL lanes active).
// fp32 accuracy via bf16 hi+lo 3-product split.

#define TT 512
#define HH 64
#define BT 8

typedef __attribute__((ext_vector_type(8))) short short8;
typedef __attribute__((ext_vector_type(4))) float f32x4;

#define MFMA16 __builtin_amdgcn_mfma_f32_16x16x32_bf16

__device__ __forceinline__ float sigm(float x) {
    return __builtin_amdgcn_rcpf(1.f + __expf(-x));
}
// NaN-safe tanh: 1 - 2/(1+e^{2x})
__device__ __forceinline__ float tanh_f(float x) {
    return 1.f - 2.f * __builtin_amdgcn_rcpf(1.f + __expf(2.f * x));
}
__device__ __forceinline__ void cvt8(const float* p, short8& hi, short8& lo) {
    #pragma unroll
    for (int i = 0; i < 8; ++i) {
        float v = p[i];
        unsigned short h = (unsigned short)(__float_as_uint(v) >> 16);
        float r = v - __uint_as_float(((unsigned)h) << 16);
        unsigned short l = (unsigned short)(__float_as_uint(r) >> 16);
        hi[i] = (short)h;
        lo[i] = (short)l;
    }
}
__device__ __forceinline__ void split1(float v, unsigned short& h, unsigned short& l) {
    h = (unsigned short)(__float_as_uint(v) >> 16);
    float r = v - __uint_as_float(((unsigned)h) << 16);
    l = (unsigned short)(__float_as_uint(r) >> 16);
}
__device__ __forceinline__ float gate4(float pi, float pf, float pg, float po, float& c) {
    float gi = sigm(pi), gf = sigm(pf), gg = tanh_f(pg), go = sigm(po);
    c = fmaf(gf, c, gi * gg);
    return go * tanh_f(c);
}
// lane i <- lane (i^8) within each row of 16 (row_ror:8). All lanes must
// be active at the call site (convergent; inactive source lanes read 0).
__device__ __forceinline__ float dpp_ror8(float v) {
    return __int_as_float(__builtin_amdgcn_update_dpp(
        0, __float_as_int(v), 0x128, 0xF, 0xF, true));
}

__global__ __launch_bounds__(1024) void lstm_mfma(
    const float* __restrict__ x,
    const float* __restrict__ Wih0, const float* __restrict__ Whh0,
    const float* __restrict__ bih0, const float* __restrict__ bhh0,
    const float* __restrict__ Wih1, const float* __restrict__ Whh1,
    const float* __restrict__ bih1, const float* __restrict__ bhh1,
    const float* __restrict__ fcW, const float* __restrict__ fcb,
    float* __restrict__ out)
{
    __shared__ float xs[BT][TT + 1];                     // 16.4 KB
    // h in MFMA B-layout: [buf][kt][hi/lo][lane][elem]; B[k][n]: n=lane&15,
    // k = kt*32 + (lane>>4)*8 + elem. Rows for n>=8 stay 0 (padding).
    __shared__ __align__(16) short aH1[2][2][2][64][8];  // 8 KB
    __shared__ __align__(16) short aH2[2][2][2][64][8];  // 8 KB
    __shared__ float hF[BT][HH + 1];
    __shared__ float fcw_s[HH];

    const int t    = threadIdx.x;
    const int lane = t & 63;
    const int w    = t >> 6;          // wave 0..15
    const bool isL1 = (w < 8);
    const int wv   = w & 7;           // group-local wave: owns M-tiles 2wv, 2wv+1
    const int b0   = blockIdx.x * BT;
    const int m    = lane & 15;       // A-row-within-tile AND D-col (=batch)
    const int q    = lane >> 4;       // quad

    // ---- stage x; zero both h buffers ----
    for (int i = t; i < BT * TT; i += 1024)
        xs[i >> 9][i & (TT - 1)] = x[(size_t)(b0 + (i >> 9)) * TT + (i & (TT - 1))];
    {
        int* z1 = (int*)aH1;
        for (int i = t; i < 2048; i += 1024) z1[i] = 0;
        int* z2 = (int*)aH2;
        for (int i = t; i < 2048; i += 1024) z2[i] = 0;
    }
    if (t < HH) fcw_s[t] = fcW[t];

    // ---- persistent A-frag weights (hi/lo): 2 tiles per wave ----
    // A-row m in tile mtg -> gate-row rho = (m&3)*64 + 4*mtg + (m>>2)
    // G1 (isL1): kt 0,1 from Whh0.  G2: kt 0,1 Wih1; kt 2,3 Whh1.
    short8 aWh[2][4], aWl[2][4];      // [i][kt]
    {
        const float* Ws01 = isL1 ? Whh0 : Wih1;
        #pragma unroll
        for (int i = 0; i < 2; ++i) {
            const int mtg = 2 * wv + i;
            const int rho = (m & 3) * 64 + 4 * mtg + (m >> 2);
            cvt8(Ws01 + rho * HH +      q * 8, aWh[i][0], aWl[i][0]);
            cvt8(Ws01 + rho * HH + 32 + q * 8, aWh[i][1], aWl[i][1]);
            if (!isL1) {
                cvt8(Whh1 + rho * HH +      q * 8, aWh[i][2], aWl[i][2]);
                cvt8(Whh1 + rho * HH + 32 + q * 8, aWh[i][3], aWl[i][3]);
            }
        }
    }

    // ---- bias in D-layout (rides the pack): biasD[i][r] for tile i,
    // D-row 4q+r -> gate-row rho = r*64 + 4*(2wv+i) + q ----
    f32x4 biasD[2];
    #pragma unroll
    for (int i = 0; i < 2; ++i)
        #pragma unroll
        for (int r = 0; r < 4; ++r) {
            const int rho = r * 64 + 4 * (2 * wv + i) + q;
            biasD[i][r] = isL1 ? (bih0[rho] + bhh0[rho])
                               : (bih1[rho] + bhh1[rho]);
        }

    // ---- packed combine constants: lane handles (jpk, bpk) ----
    const int ts  = (m >> 3) & 1;
    const int jpk = 8 * wv + 4 * ts + q;   // this lane's hidden unit
    const int bpk = m & 7;                 // this lane's batch
    float wxb[4];
    #pragma unroll
    for (int v = 0; v < 4; ++v)
        wxb[v] = isL1 ? Wih0[v * 64 + jpk] : 0.f;
    // scatter indices for (jpk, bpk) into B-layout
    const int skt = jpk >> 5;
    const int ssl = bpk + 16 * ((jpk >> 3) & 3);
    const int sse = jpk & 7;
    float c = 0.f;

    __syncthreads();

    #pragma unroll 2
    for (int k = 0; k < TT; ++k) {
        const int p = k & 1, pn = p ^ 1;

        if (isL1) {
            // ---- G1: h1(k) from h1(k-1) ----
            short8 bh0 = *(const short8*)&aH1[p][0][0][lane][0];
            short8 bl0 = *(const short8*)&aH1[p][0][1][lane][0];
            short8 bh1 = *(const short8*)&aH1[p][1][0][lane][0];
            short8 bl1 = *(const short8*)&aH1[p][1][1][lane][0];
            f32x4 acc0 = biasD[0], acc1 = biasD[1];
            acc0 = MFMA16(aWh[0][0], bh0, acc0, 0, 0, 0);
            acc1 = MFMA16(aWh[1][0], bh0, acc1, 0, 0, 0);
            acc0 = MFMA16(aWl[0][0], bh0, acc0, 0, 0, 0);
            acc1 = MFMA16(aWl[1][0], bh0, acc1, 0, 0, 0);
            acc0 = MFMA16(aWh[0][0], bl0, acc0, 0, 0, 0);
            acc1 = MFMA16(aWh[1][0], bl0, acc1, 0, 0, 0);
            acc0 = MFMA16(aWh[0][1], bh1, acc0, 0, 0, 0);
            acc1 = MFMA16(aWh[1][1], bh1, acc1, 0, 0, 0);
            acc0 = MFMA16(aWl[0][1], bh1, acc0, 0, 0, 0);
            acc1 = MFMA16(aWl[1][1], bh1, acc1, 0, 0, 0);
            acc0 = MFMA16(aWh[0][1], bl1, acc0, 0, 0, 0);
            acc1 = MFMA16(aWh[1][1], bl1, acc1, 0, 0, 0);
            // DPP unconditionally (all lanes active), THEN select.
            f32x4 mv, pk;
            #pragma unroll
            for (int r = 0; r < 4; ++r) mv[r] = dpp_ror8(acc1[r]);
            #pragma unroll
            for (int r = 0; r < 4; ++r) pk[r] = (m < 8) ? acc0[r] : mv[r];
            float xb = xs[bpk][k];
            float h1 = gate4(fmaf(wxb[0], xb, pk[0]),
                             fmaf(wxb[1], xb, pk[1]),
                             fmaf(wxb[2], xb, pk[2]),
                             fmaf(wxb[3], xb, pk[3]), c);
            unsigned short hh, hl;
            split1(h1, hh, hl);
            aH1[pn][skt][0][ssl][sse] = (short)hh;
            aH1[pn][skt][1][ssl][sse] = (short)hl;
        } else if (k > 0) {
            // ---- G2: h2(k-1) from h1(k-1), h2(k-2) ----
            short8 b1h0 = *(const short8*)&aH1[p][0][0][lane][0];
            short8 b1l0 = *(const short8*)&aH1[p][0][1][lane][0];
            short8 b1h1 = *(const short8*)&aH1[p][1][0][lane][0];
            short8 b1l1 = *(const short8*)&aH1[p][1][1][lane][0];
            short8 b2h0 = *(const short8*)&aH2[p][0][0][lane][0];
            short8 b2l0 = *(const short8*)&aH2[p][0][1][lane][0];
            short8 b2h1 = *(const short8*)&aH2[p][1][0][lane][0];
            short8 b2l1 = *(const short8*)&aH2[p][1][1][lane][0];
            f32x4 acc0 = biasD[0], acc1 = biasD[1];
            acc0 = MFMA16(aWh[0][0], b1h0, acc0, 0, 0, 0);
            acc1 = MFMA16(aWh[1][0], b1h0, acc1, 0, 0, 0);
            acc0 = MFMA16(aWl[0][0], b1h0, acc0, 0, 0, 0);
            acc1 = MFMA16(aWl[1][0], b1h0, acc1, 0, 0, 0);
            acc0 = MFMA16(aWh[0][0], b1l0, acc0, 0, 0, 0);
            acc1 = MFMA16(aWh[1][0], b1l0, acc1, 0, 0, 0);
            acc0 = MFMA16(aWh[0][1], b1h1, acc0, 0, 0, 0);
            acc1 = MFMA16(aWh[1][1], b1h1, acc1, 0, 0, 0);
            acc0 = MFMA16(aWl[0][1], b1h1, acc0, 0, 0, 0);
            acc1 = MFMA16(aWl[1][1], b1h1, acc1, 0, 0, 0);
            acc0 = MFMA16(aWh[0][1], b1l1, acc0, 0, 0, 0);
            acc1 = MFMA16(aWh[1][1], b1l1, acc1, 0, 0, 0);
            acc0 = MFMA16(aWh[0][2], b2h0, acc0, 0, 0, 0);
            acc1 = MFMA16(aWh[1][2], b2h0, acc1, 0, 0, 0);
            acc0 = MFMA16(aWl[0][2], b2h0, acc0, 0, 0, 0);
            acc1 = MFMA16(aWl[1][2], b2h0, acc1, 0, 0, 0);
            acc0 = MFMA16(aWh[0][2], b2l0, acc0, 0, 0, 0);
            acc1 = MFMA16(aWh[1][2], b2l0, acc1, 0, 0, 0);
            acc0 = MFMA16(aWh[0][3], b2h1, acc0, 0, 0, 0);
            acc1 = MFMA16(aWh[1][3], b2h1, acc1, 0, 0, 0);
            acc0 = MFMA16(aWl[0][3], b2h1, acc0, 0, 0, 0);
            acc1 = MFMA16(aWl[1][3], b2h1, acc1, 0, 0, 0);
            acc0 = MFMA16(aWh[0][3], b2l1, acc0, 0, 0, 0);
            acc1 = MFMA16(aWh[1][3], b2l1, acc1, 0, 0, 0);
            f32x4 mv, pk;
            #pragma unroll
            for (int r = 0; r < 4; ++r) mv[r] = dpp_ror8(acc1[r]);
            #pragma unroll
            for (int r = 0; r < 4; ++r) pk[r] = (m < 8) ? acc0[r] : mv[r];
            float h2 = gate4(pk[0], pk[1], pk[2], pk[3], c);
            unsigned short hh, hl;
            split1(h2, hh, hl);
            aH2[pn][skt][0][ssl][sse] = (short)hh;
            aH2[pn][skt][1][ssl][sse] = (short)hl;
        }
        __syncthreads();
    }

    // ---- epilogue: h2(TT-1) from h1(TT-1) (aH1[0]) and h2(TT-2) (aH2[0]) ----
    if (!isL1) {
        short8 b1h0 = *(const short8*)&aH1[0][0][0][lane][0];
        short8 b1l0 = *(const short8*)&aH1[0][0][1][lane][0];
        short8 b1h1 = *(const short8*)&aH1[0][1][0][lane][0];
        short8 b1l1 = *(const short8*)&aH1[0][1][1][lane][0];
        short8 b2h0 = *(const short8*)&aH2[0][0][0][lane][0];
        short8 b2l0 = *(const short8*)&aH2[0][0][1][lane][0];
        short8 b2h1 = *(const short8*)&aH2[0][1][0][lane][0];
        short8 b2l1 = *(const short8*)&aH2[0][1][1][lane][0];
        f32x4 acc0 = biasD[0], acc1 = biasD[1];
        acc0 = MFMA16(aWh[0][0], b1h0, acc0, 0, 0, 0);
        acc1 = MFMA16(aWh[1][0], b1h0, acc1, 0, 0, 0);
        acc0 = MFMA16(aWl[0][0], b1h0, acc0, 0, 0, 0);
        acc1 = MFMA16(aWl[1][0], b1h0, acc1, 0, 0, 0);
        acc0 = MFMA16(aWh[0][0], b1l0, acc0, 0, 0, 0);
        acc1 = MFMA16(aWh[1][0], b1l0, acc1, 0, 0, 0);
        acc0 = MFMA16(aWh[0][1], b1h1, acc0, 0, 0, 0);
        acc1 = MFMA16(aWh[1][1], b1h1, acc1, 0, 0, 0);
        acc0 = MFMA16(aWl[0][1], b1h1, acc0, 0, 0, 0);
        acc1 = MFMA16(aWl[1][1], b1h1, acc1, 0, 0, 0);
        acc0 = MFMA16(aWh[0][1], b1l1, acc0, 0, 0, 0);
        acc1 = MFMA16(aWh[1][1], b1l1, acc1, 0, 0, 0);
        acc0 = MFMA16(aWh[0][2], b2h0, acc0, 0, 0, 0);
        acc1 = MFMA16(aWh[1][2], b2h0, acc1, 0, 0, 0);
        acc0 = MFMA16(aWl[0][2], b2h0, acc0, 0, 0, 0);
        acc1 = MFMA16(aWl[1][2], b2h0, acc1, 0, 0, 0);
        acc0 = MFMA16(aWh[0][2], b2l0, acc0, 0, 0, 0);
        acc1 = MFMA16(aWh[1][2], b2l0, acc1, 0, 0, 0);
        acc0 = MFMA16(aWh[0][3], b2h1, acc0, 0, 0, 0);
        acc1 = MFMA16(aWh[1][3], b2h1, acc1, 0, 0, 0);
        acc0 = MFMA16(aWl[0][3], b2h1, acc0, 0, 0, 0);
        acc1 = MFMA16(aWl[1][3], b2h1, acc1, 0, 0, 0);
        acc0 = MFMA16(aWh[0][3], b2l1, acc0, 0, 0, 0);
        acc1 = MFMA16(aWh[1][3], b2l1, acc1, 0, 0, 0);
        f32x4 mv, pk;
        #pragma unroll
        for (int r = 0; r < 4; ++r) mv[r] = dpp_ror8(acc1[r]);
        #pragma unroll
        for (int r = 0; r < 4; ++r) pk[r] = (m < 8) ? acc0[r] : mv[r];
        float h2 = gate4(pk[0], pk[1], pk[2], pk[3], c);
        hF[bpk][jpk] = h2;
    }
    __syncthreads();

    // ---- final FC: out[b] = fcW . h2(TT-1)[b] + fcb ----
    if (t < BT) {
        float s = fcb[0];
        #pragma unroll 8
        for (int j = 0; j < HH; ++j)
            s = fmaf(hF[t][j], fcw_s[j], s);
        out[b0 + t] = s;
    }
}

extern "C" void kernel_launch(void* const* d_in, const int* in_sizes, int n_in,
                              void* d_out, int out_size, void* d_ws, size_t ws_size,
                              hipStream_t stream) {
    const float* x    = (const float*)d_in[0];
    const float* Wih0 = (const float*)d_in[1];
    const float* Whh0 = (const float*)d_in[2];
    const float* bih0 = (const float*)d_in[3];
    const float* bhh0 = (const float*)d_in[4];
    const float* Wih1 = (const float*)d_in[5];
    const float* Whh1 = (const float*)d_in[6];
    const float* bih1 = (const float*)d_in[7];
    const float* bhh1 = (const float*)d_in[8];
    const float* fcW  = (const float*)d_in[9];
    const float* fcb  = (const float*)d_in[10];
    float* out = (float*)d_out;

    lstm_mfma<<<dim3(2048 / BT), dim3(1024), 0, stream>>>(
        x, Wih0, Whh0, bih0, bhh0, Wih1, Whh1, bih1, bhh1, fcW, fcb, out);
}